// Round 7
// baseline (416.368 us; speedup 1.0000x reference)
//
#include <hip/hip_runtime.h>
#include <cstdint>
#include <cstddef>

// ---------------------------------------------------------------------------
// WindowGCN: 2-layer GCN + mean-pool + linear head.
// R7: gather payloads quantized to int8 + per-row scale (dinv folded into
//     scale) -- halves the random-gather L2-miss bytes that sit on the
//     measured ~3.9 TB/s wall. GEMM1 epilogue emits int8+scale directly
//     (LDS row-max). Mean-pool fused into GEMM2 epilogue (no h2 buffer).
//     CSR build via 2-level bucket sort (R6). MFMA bf16 GEMMs (R4/R5).
// ---------------------------------------------------------------------------

typedef __attribute__((ext_vector_type(8))) short bf16x8;
typedef __attribute__((ext_vector_type(4))) float f32x4;

#define P1_CHUNK 4096
#define BCAP 8192  // pairs capacity per 256-node bucket (mean 4093)

__device__ inline unsigned short f2bf(float f) {  // RNE fp32 -> bf16
    unsigned u = __float_as_uint(f);
    u = (u + 0x7FFFu + ((u >> 16) & 1u)) >> 16;
    return (unsigned short)u;
}

// ---------------- CSR build: pass 1 (coarse bucket scatter) ----------------
__global__ __launch_bounds__(256) void bucket_scatter_kernel(
        const int* __restrict__ src, const int* __restrict__ dst,
        int* __restrict__ bucketCnt, unsigned long long* __restrict__ pairs,
        int E, int NB) {
    __shared__ int hist[512];
    __shared__ int base[512];
    int t = threadIdx.x;
    int e0 = blockIdx.x * P1_CHUNK;
    int eend = min(e0 + P1_CHUNK, E);
    for (int i = t; i < NB; i += 256) hist[i] = 0;
    __syncthreads();
    for (int e = e0 + t; e < eend; e += 256) atomicAdd(&hist[dst[e] >> 8], 1);
    __syncthreads();
    for (int i = t; i < NB; i += 256) {
        int c = hist[i];
        base[i] = (c > 0) ? atomicAdd(&bucketCnt[i], c) : 0;
        hist[i] = 0;  // reuse as cursor
    }
    __syncthreads();
    for (int e = e0 + t; e < eend; e += 256) {
        int d = dst[e], s = src[e];
        int b = d >> 8;
        int r = base[b] + atomicAdd(&hist[b], 1);
        if (r < BCAP)
            pairs[(size_t)b * BCAP + r] =
                (unsigned long long)(unsigned)s | ((unsigned long long)(d & 255) << 32);
    }
}

// 391-entry exclusive scan of bucket counts (one block), + off[N] sentinel.
__global__ __launch_bounds__(512) void bucket_scan_kernel(
        const int* __restrict__ cnt, int* __restrict__ bbase,
        int* __restrict__ off, int NB, int N, int E) {
    __shared__ int wsum[8];
    int t = threadIdx.x, lane = t & 63, w = t >> 6;
    int v = (t < NB) ? cnt[t] : 0;
    int x = v;
    #pragma unroll
    for (int d = 1; d < 64; d <<= 1) {
        int y = __shfl_up(x, d, 64);
        if (lane >= d) x += y;
    }
    if (lane == 63) wsum[w] = x;
    __syncthreads();
    int woff = 0;
    #pragma unroll
    for (int j = 0; j < 8; j++)
        if (j < w) woff += wsum[j];
    if (t < NB) bbase[t] = woff + x - v;
    if (t == 0) off[N] = E;
}

// ---------------- CSR build: pass 2 (per-bucket counting sort) -------------
__global__ __launch_bounds__(256) void fine_place_kernel(
        const unsigned long long* __restrict__ pairs, const int* __restrict__ bucketCnt,
        const int* __restrict__ bucketBase, int* __restrict__ off,
        float* __restrict__ dinv, int* __restrict__ csr, int N) {
    __shared__ int hist[256];
    __shared__ int loff[256];
    __shared__ int ws[4];
    int b = blockIdx.x, t = threadIdx.x;
    int cnt = min(bucketCnt[b], BCAP), base = bucketBase[b];
    const unsigned long long* pp = pairs + (size_t)b * BCAP;
    hist[t] = 0;
    __syncthreads();
    for (int i = t; i < cnt; i += 256) atomicAdd(&hist[(int)(pp[i] >> 32)], 1);
    __syncthreads();
    int v = hist[t];
    {
        int lane = t & 63, w = t >> 6;
        int x = v;
        #pragma unroll
        for (int d = 1; d < 64; d <<= 1) {
            int y = __shfl_up(x, d, 64);
            if (lane >= d) x += y;
        }
        if (lane == 63) ws[w] = x;
        __syncthreads();
        int woff = 0;
        #pragma unroll
        for (int j = 0; j < 4; j++)
            if (j < w) woff += ws[j];
        loff[t] = woff + x - v;
    }
    int node = b * 256 + t;
    if (node < N) {
        off[node] = base + loff[t];
        dinv[node] = rsqrtf((float)v + 1.0f);  // +1 self-loop
    }
    __syncthreads();
    hist[t] = 0;  // cursors
    __syncthreads();
    for (int i = t; i < cnt; i += 256) {
        unsigned long long pr = pp[i];
        int dl = (int)(pr >> 32);
        int r = atomicAdd(&hist[dl], 1);
        csr[base + loff[dl] + r] = (int)(unsigned)pr;
    }
}

// ---------------- misc prep ----------------

__global__ __launch_bounds__(256) void graph_count_kernel(const int* __restrict__ batch,
                                                          int* __restrict__ cnt, int N) {
    __shared__ int h[256];
    int t = threadIdx.x;
    h[t] = 0;
    __syncthreads();
    int n = blockIdx.x * 256 + t;
    if (n < N) atomicAdd(&h[batch[n]], 1);
    __syncthreads();
    if (h[t] != 0) atomicAdd(&cnt[t], h[t]);
}

// x [N][128] fp32 -> Q int8 [N][128] + scale0[i] = dinv[i]*rowmax/127.
// One wave per node; lane holds 2 columns.
__global__ __launch_bounds__(256) void prescale_q8_kernel(
        const float* __restrict__ x, const float* __restrict__ dinv,
        unsigned short* __restrict__ Q, float* __restrict__ scale, int N) {
    int node = blockIdx.x * 4 + (threadIdx.x >> 6);
    int lane = threadIdx.x & 63;
    if (node >= N) return;
    float2 v = reinterpret_cast<const float2*>(x)[(size_t)node * 64 + lane];
    float m = fmaxf(fabsf(v.x), fabsf(v.y));
    #pragma unroll
    for (int d = 32; d >= 1; d >>= 1) m = fmaxf(m, __shfl_xor(m, d, 64));
    float qinv = m > 0.f ? 127.f / m : 0.f;
    int q0 = (int)rintf(v.x * qinv), q1 = (int)rintf(v.y * qinv);
    Q[(size_t)node * 64 + lane] = (unsigned short)((q0 & 255) | ((q1 & 255) << 8));
    if (lane == 0) scale[node] = dinv[node] * m * (1.f / 127.f);
}

// W [K][256] fp32 -> WT [256][K] bf16
__global__ __launch_bounds__(256) void transpose_w_kernel(const float* __restrict__ W,
                                                          unsigned short* __restrict__ WT,
                                                          int K) {
    int idx = blockIdx.x * 256 + threadIdx.x;
    if (idx < K * 256) {
        int k = idx >> 8, n = idx & 255;
        WT[n * K + k] = f2bf(W[idx]);
    }
}

// -------- aggregation: OUT(bf16) = dinv[i] * sum(scale[s] * q8row[s]) ------
// One wave per node (scalarized); lane owns VEC int8 cols; 16x-unrolled.
template <int VEC>  // 2 (layer1, 128-d) or 4 (layer2, 256-d)
__global__ __launch_bounds__(256) void aggregate_q8_kernel(
        const void* __restrict__ Qv, const float* __restrict__ scale,
        unsigned short* __restrict__ OUT,
        const int* __restrict__ off, const int* __restrict__ csr,
        const float* __restrict__ dinv, int N) {
    int node = __builtin_amdgcn_readfirstlane(blockIdx.x * 4 + (threadIdx.x >> 6));
    int lane = threadIdx.x & 63;
    if (node >= N) return;

    float acc[VEC];
    auto loadpay = [&](int s) -> unsigned {
        if constexpr (VEC == 4)
            return reinterpret_cast<const unsigned*>(Qv)[(size_t)s * 64 + lane];
        else
            return (unsigned)reinterpret_cast<const unsigned short*>(Qv)[(size_t)s * 64 + lane];
    };
    auto addrow = [&](unsigned v, float sc) {
        #pragma unroll
        for (int j = 0; j < VEC; j++)
            acc[j] += sc * (float)(int)(signed char)(v >> (8 * j));
    };
    {
        unsigned v = loadpay(node);
        float sc = scale[node];
        #pragma unroll
        for (int j = 0; j < VEC; j++)
            acc[j] = sc * (float)(int)(signed char)(v >> (8 * j));
    }
    int e0 = off[node], e1 = off[node + 1];
    int e = e0;
    for (; e + 16 <= e1; e += 16) {
        int s[16]; unsigned v[16]; float sc[16];
        #pragma unroll
        for (int j = 0; j < 16; j++) s[j] = csr[e + j];
        #pragma unroll
        for (int j = 0; j < 16; j++) { v[j] = loadpay(s[j]); sc[j] = scale[s[j]]; }
        #pragma unroll
        for (int j = 0; j < 16; j++) addrow(v[j], sc[j]);
    }
    if (e + 8 <= e1) {
        int s[8]; unsigned v[8]; float sc[8];
        #pragma unroll
        for (int j = 0; j < 8; j++) s[j] = csr[e + j];
        #pragma unroll
        for (int j = 0; j < 8; j++) { v[j] = loadpay(s[j]); sc[j] = scale[s[j]]; }
        #pragma unroll
        for (int j = 0; j < 8; j++) addrow(v[j], sc[j]);
        e += 8;
    }
    for (; e < e1; e++) { unsigned v = loadpay(csr[e]); addrow(v, scale[csr[e]]); }

    float di = dinv[node];
    if constexpr (VEC == 4) {
        uint2 o;
        o.x = (unsigned)f2bf(di * acc[0]) | ((unsigned)f2bf(di * acc[1]) << 16);
        o.y = (unsigned)f2bf(di * acc[2]) | ((unsigned)f2bf(di * acc[3]) << 16);
        reinterpret_cast<uint2*>(OUT)[(size_t)node * 64 + lane] = o;
    } else {
        unsigned o = (unsigned)f2bf(di * acc[0]) | ((unsigned)f2bf(di * acc[1]) << 16);
        reinterpret_cast<unsigned*>(OUT)[(size_t)node * 64 + lane] = o;
    }
}

// ---------------- MFMA GEMM ----------------
// relu(A[M][K]@W + bias); A bf16 row-major, WT=W^T bf16. 256 thr / 4 waves,
// tile 64x256; A (8KB) + W^T k-chunk (32KB) in LDS via pre-swizzled
// global_load_lds (XOR (r&7)<<4 kills stride-128B conflicts).
// MODE 0 (layer1): emit int8 Y1q[m][256] + scaleOut[m]=dinv[m]*rowmax/127.
// MODE 1 (layer2): fused mean-pool -- accumulate per-graph sums into gsum.
template <int K, int MODE>
__global__ __launch_bounds__(256) void mfma_gemm_kernel(
        const unsigned short* __restrict__ A, const unsigned short* __restrict__ WT,
        const float* __restrict__ bias, const float* __restrict__ dinv,
        char* __restrict__ Cq, float* __restrict__ scaleOut,
        const int* __restrict__ batch, float* __restrict__ gsum, int M) {
    __shared__ unsigned short As[64 * 64];
    __shared__ unsigned short Ws[256 * 64];
    __shared__ int rowmaxi[64];
    __shared__ float lsum[4 * 256];
    const int t = threadIdx.x;
    const int lane = t & 63, w = t >> 6;
    const int r0 = blockIdx.x * 64;
    const int lhi = lane >> 4, l15 = lane & 15;

    f32x4 acc[4][4];
    #pragma unroll
    for (int i = 0; i < 4; i++)
        #pragma unroll
        for (int j = 0; j < 4; j++) acc[i][j] = (f32x4){0.f, 0.f, 0.f, 0.f};

    for (int k0 = 0; k0 < K; k0 += 64) {
        #pragma unroll
        for (int p = 0; p < 2; p++) {  // A: 512 x 16B chunks
            int idx = p * 256 + t;
            int row = idx >> 3;
            int sbyte = ((idx & 7) * 16) ^ ((row & 7) << 4);
            const char* g = (const char*)(A + (size_t)(r0 + row) * K + k0) + sbyte;
            __builtin_amdgcn_global_load_lds(
                (const __attribute__((address_space(1))) void*)g,
                (__attribute__((address_space(3))) void*)((char*)As + idx * 16),
                16, 0, 0);
        }
        #pragma unroll
        for (int q = 0; q < 8; q++) {  // W^T chunk: 2048 x 16B chunks
            int idx = q * 256 + t;
            int col = idx >> 3;
            int sbyte = ((idx & 7) * 16) ^ ((col & 7) << 4);
            const char* g = (const char*)(WT + (size_t)col * K + k0) + sbyte;
            __builtin_amdgcn_global_load_lds(
                (const __attribute__((address_space(1))) void*)g,
                (__attribute__((address_space(3))) void*)((char*)Ws + idx * 16),
                16, 0, 0);
        }
        __syncthreads();
        #pragma unroll
        for (int kk = 0; kk < 64; kk += 32) {
            bf16x8 a[4], b[4];
            int kb = (kk + lhi * 8) * 2;
            #pragma unroll
            for (int mf = 0; mf < 4; mf++) {
                int row = mf * 16 + l15;
                a[mf] = *reinterpret_cast<const bf16x8*>(
                    (const char*)As + row * 128 + (kb ^ ((row & 7) << 4)));
            }
            #pragma unroll
            for (int nf = 0; nf < 4; nf++) {
                int col = w * 64 + nf * 16 + l15;
                b[nf] = *reinterpret_cast<const bf16x8*>(
                    (const char*)Ws + col * 128 + (kb ^ ((col & 7) << 4)));
            }
            #pragma unroll
            for (int mf = 0; mf < 4; mf++)
                #pragma unroll
                for (int nf = 0; nf < 4; nf++)
                    acc[mf][nf] = __builtin_amdgcn_mfma_f32_16x16x32_bf16(
                        a[mf], b[nf], acc[mf][nf], 0, 0, 0);
        }
        __syncthreads();
    }

    float bn[4];
    #pragma unroll
    for (int nf = 0; nf < 4; nf++) bn[nf] = bias[w * 64 + nf * 16 + l15];

    if constexpr (MODE == 0) {
        if (t < 64) rowmaxi[t] = 0;
        __syncthreads();
        #pragma unroll
        for (int mf = 0; mf < 4; mf++) {
            #pragma unroll
            for (int j = 0; j < 4; j++) {
                float lmax = 0.f;
                #pragma unroll
                for (int nf = 0; nf < 4; nf++) {
                    float vv = fmaxf(acc[mf][nf][j] + bn[nf], 0.f);
                    acc[mf][nf][j] = vv;
                    lmax = fmaxf(lmax, vv);
                }
                atomicMax(&rowmaxi[mf * 16 + lhi * 4 + j], __float_as_int(lmax));
            }
        }
        __syncthreads();
        #pragma unroll
        for (int mf = 0; mf < 4; mf++) {
            #pragma unroll
            for (int j = 0; j < 4; j++) {
                int r = mf * 16 + lhi * 4 + j;
                int m = r0 + r;
                if (m < M) {
                    float rm = __int_as_float(rowmaxi[r]);
                    float qinv = rm > 0.f ? 127.f / rm : 0.f;
                    #pragma unroll
                    for (int nf = 0; nf < 4; nf++) {
                        int n = w * 64 + nf * 16 + l15;
                        Cq[(size_t)m * 256 + n] = (char)(int)rintf(acc[mf][nf][j] * qinv);
                    }
                    if (w == 0 && l15 == 0)
                        scaleOut[m] = dinv[m] * rm * (1.f / 127.f);
                }
            }
        }
    } else {
        for (int i = t; i < 1024; i += 256) lsum[i] = 0.f;
        int gmin = batch[r0];
        int gmax = batch[min(r0 + 63, M - 1)];
        int nslot = gmax - gmin + 1;
        bool fits = nslot <= 4;
        __syncthreads();
        #pragma unroll
        for (int mf = 0; mf < 4; mf++) {
            #pragma unroll
            for (int j = 0; j < 4; j++) {
                int m = r0 + mf * 16 + lhi * 4 + j;
                if (m < M) {
                    int g = batch[m];
                    #pragma unroll
                    for (int nf = 0; nf < 4; nf++) {
                        int n = w * 64 + nf * 16 + l15;
                        float vv = fmaxf(acc[mf][nf][j] + bn[nf], 0.f);
                        if (fits) atomicAdd(&lsum[(g - gmin) * 256 + n], vv);
                        else      atomicAdd(&gsum[(size_t)g * 256 + n], vv);
                    }
                }
            }
        }
        __syncthreads();
        if (fits) {
            for (int s = 0; s < nslot; s++)
                atomicAdd(&gsum[(size_t)(gmin + s) * 256 + t], lsum[s * 256 + t]);
        }
    }
}

// ---------------- final pool-divide + classifier head ----------------

__global__ __launch_bounds__(256) void pool_final_kernel(const float* __restrict__ gsum,
                                                         const int* __restrict__ cnt,
                                                         const float* __restrict__ Wc,
                                                         const float* __restrict__ bc,
                                                         float* __restrict__ out) {
    __shared__ float gm[256];
    int g = blockIdx.x, t = threadIdx.x;
    float inv = 1.0f / fmaxf((float)cnt[g], 1.0f);
    gm[t] = gsum[g * 256 + t] * inv;
    __syncthreads();
    if (t < 200) {
        float acc = bc[t];
        #pragma unroll 8
        for (int k = 0; k < 256; k++) acc += gm[k] * Wc[k * 200 + t];
        out[g * 200 + t] = acc;
    }
}

// ---------------- driver ----------------

extern "C" void kernel_launch(void* const* d_in, const int* in_sizes, int n_in,
                              void* d_out, int out_size, void* d_ws, size_t ws_size,
                              hipStream_t stream) {
    const float* x   = (const float*)d_in[0];
    const int* ei    = (const int*)d_in[1];
    const int* batch = (const int*)d_in[2];
    const float* W1  = (const float*)d_in[4];
    const float* b1  = (const float*)d_in[5];
    const float* W2  = (const float*)d_in[6];
    const float* b2  = (const float*)d_in[7];
    const float* Wc  = (const float*)d_in[8];
    const float* bc  = (const float*)d_in[9];
    float* out = (float*)d_out;

    const int N = in_sizes[2];       // 100000
    const int E = in_sizes[1] / 2;   // 1600000
    const int G = out_size / 200;    // 64
    const int K1 = in_sizes[0] / N;  // 128
    const int Mpad = (N + 63) & ~63; // 100032
    const int NB = (N + 255) >> 8;   // 391
    const int* src = ei;
    const int* dst = ei + E;

    char* p = (char*)d_ws;
    auto alloc = [&](size_t bytes) -> char* {
        char* r = p;
        p += (bytes + 255) & ~(size_t)255;
        return r;
    };
    int*   off    = (int*)alloc((size_t)(N + 1) * 4);
    int*   bktCnt = (int*)alloc((size_t)NB * 4);
    int*   bktBase= (int*)alloc((size_t)NB * 4);
    int*   cnt    = (int*)alloc(256 * 4);
    float* dinv   = (float*)alloc((size_t)N * 4);
    float* scale0 = (float*)alloc((size_t)N * 4);
    float* scale1 = (float*)alloc((size_t)N * 4);
    float* gsum   = (float*)alloc((size_t)G * 256 * 4);
    int*   csr    = (int*)alloc((size_t)E * 4);
    unsigned long long* pairs = (unsigned long long*)alloc((size_t)NB * BCAP * 8);
    unsigned short* WT1 = (unsigned short*)alloc((size_t)256 * K1 * 2);
    unsigned short* WT2 = (unsigned short*)alloc((size_t)256 * 256 * 2);
    char* slotA = alloc((size_t)N * 256);          // Y0q (12.8MB) -> Y1q (25.6MB)
    char* slotB = alloc((size_t)Mpad * 256 * 2);   // a1 (25.6MB) -> a2 (51.2MB)
    unsigned short* Y0q = (unsigned short*)slotA;  // [N][128] int8 as ushort pairs
    char*           Y1q = slotA;                   // [N][256] int8
    unsigned short* a1  = (unsigned short*)slotB;  // [Mpad][128] bf16
    unsigned short* a2  = (unsigned short*)slotB;  // [Mpad][256] bf16

    hipMemsetAsync(bktCnt, 0, (size_t)NB * 4, stream);
    hipMemsetAsync(cnt, 0, 256 * 4, stream);
    hipMemsetAsync(gsum, 0, (size_t)G * 256 * 4, stream);

    int blkN = (N + 255) / 256;
    // CSR build (produces off, dinv)
    bucket_scatter_kernel<<<(E + P1_CHUNK - 1) / P1_CHUNK, 256, 0, stream>>>(
        src, dst, bktCnt, pairs, E, NB);
    bucket_scan_kernel<<<1, 512, 0, stream>>>(bktCnt, bktBase, off, NB, N, E);
    fine_place_kernel<<<NB, 256, 0, stream>>>(pairs, bktCnt, bktBase, off, dinv, csr, N);

    graph_count_kernel<<<blkN, 256, 0, stream>>>(batch, cnt, N);
    transpose_w_kernel<<<(K1 * 256 + 255) / 256, 256, 0, stream>>>(W1, WT1, K1);
    transpose_w_kernel<<<(256 * 256 + 255) / 256, 256, 0, stream>>>(W2, WT2, 256);
    prescale_q8_kernel<<<(N + 3) / 4, 256, 0, stream>>>(x, dinv, Y0q, scale0, N);

    int gemm_blocks = Mpad / 64;
    // layer 1
    aggregate_q8_kernel<2><<<(N + 3) / 4, 256, 0, stream>>>(Y0q, scale0, a1, off, csr, dinv, N);
    mfma_gemm_kernel<128, 0><<<gemm_blocks, 256, 0, stream>>>(
        a1, WT1, b1, dinv, Y1q, scale1, nullptr, nullptr, N);
    // layer 2
    aggregate_q8_kernel<4><<<(N + 3) / 4, 256, 0, stream>>>(Y1q, scale1, a2, off, csr, dinv, N);
    mfma_gemm_kernel<256, 1><<<gemm_blocks, 256, 0, stream>>>(
        a2, WT2, b2, nullptr, nullptr, nullptr, batch, gsum, N);
    // head
    pool_final_kernel<<<G, 256, 0, stream>>>(gsum, cnt, Wc, bc, out);
}

// Round 8
// 336.904 us; speedup vs baseline: 1.2359x; 1.2359x over previous
//
#include <hip/hip_runtime.h>
#include <cstdint>
#include <cstddef>

// ---------------------------------------------------------------------------
// WindowGCN: 2-layer GCN + mean-pool + linear head.
// R8: GEMM restructured -- W^T preloaded into REGISTERS (once per block),
//     A double-buffered in LDS via global_load_lds with 2-phase pipeline
//     (stage tile t+1 || compute tile t), grid-stride persistent blocks.
//     MODE0 epilogue: shfl row-max + LDS pack + coalesced dwordx4 stores.
//     MODE1 epilogue: fused mean-pool, register partial sums (no LDS atomics).
//     Gather payloads int8+scale (R7), CSR via 2-level bucket sort (R6).
// ---------------------------------------------------------------------------

typedef __attribute__((ext_vector_type(8))) short bf16x8;
typedef __attribute__((ext_vector_type(4))) float f32x4;

#define P1_CHUNK 4096
#define BCAP 8192  // pairs capacity per 256-node bucket (mean 4093)

__device__ inline unsigned short f2bf(float f) {  // RNE fp32 -> bf16
    unsigned u = __float_as_uint(f);
    u = (u + 0x7FFFu + ((u >> 16) & 1u)) >> 16;
    return (unsigned short)u;
}

// ---------------- CSR build: pass 1 (coarse bucket scatter) ----------------
__global__ __launch_bounds__(256) void bucket_scatter_kernel(
        const int* __restrict__ src, const int* __restrict__ dst,
        int* __restrict__ bucketCnt, unsigned long long* __restrict__ pairs,
        int E, int NB) {
    __shared__ int hist[512];
    __shared__ int base[512];
    int t = threadIdx.x;
    int e0 = blockIdx.x * P1_CHUNK;
    int eend = min(e0 + P1_CHUNK, E);
    for (int i = t; i < NB; i += 256) hist[i] = 0;
    __syncthreads();
    for (int e = e0 + t; e < eend; e += 256) atomicAdd(&hist[dst[e] >> 8], 1);
    __syncthreads();
    for (int i = t; i < NB; i += 256) {
        int c = hist[i];
        base[i] = (c > 0) ? atomicAdd(&bucketCnt[i], c) : 0;
        hist[i] = 0;  // reuse as cursor
    }
    __syncthreads();
    for (int e = e0 + t; e < eend; e += 256) {
        int d = dst[e], s = src[e];
        int b = d >> 8;
        int r = base[b] + atomicAdd(&hist[b], 1);
        if (r < BCAP)
            pairs[(size_t)b * BCAP + r] =
                (unsigned long long)(unsigned)s | ((unsigned long long)(d & 255) << 32);
    }
}

__global__ __launch_bounds__(512) void bucket_scan_kernel(
        const int* __restrict__ cnt, int* __restrict__ bbase,
        int* __restrict__ off, int NB, int N, int E) {
    __shared__ int wsum[8];
    int t = threadIdx.x, lane = t & 63, w = t >> 6;
    int v = (t < NB) ? cnt[t] : 0;
    int x = v;
    #pragma unroll
    for (int d = 1; d < 64; d <<= 1) {
        int y = __shfl_up(x, d, 64);
        if (lane >= d) x += y;
    }
    if (lane == 63) wsum[w] = x;
    __syncthreads();
    int woff = 0;
    #pragma unroll
    for (int j = 0; j < 8; j++)
        if (j < w) woff += wsum[j];
    if (t < NB) bbase[t] = woff + x - v;
    if (t == 0) off[N] = E;
}

__global__ __launch_bounds__(256) void fine_place_kernel(
        const unsigned long long* __restrict__ pairs, const int* __restrict__ bucketCnt,
        const int* __restrict__ bucketBase, int* __restrict__ off,
        float* __restrict__ dinv, int* __restrict__ csr, int N) {
    __shared__ int hist[256];
    __shared__ int loff[256];
    __shared__ int ws[4];
    int b = blockIdx.x, t = threadIdx.x;
    int cnt = min(bucketCnt[b], BCAP), base = bucketBase[b];
    const unsigned long long* pp = pairs + (size_t)b * BCAP;
    hist[t] = 0;
    __syncthreads();
    for (int i = t; i < cnt; i += 256) atomicAdd(&hist[(int)(pp[i] >> 32)], 1);
    __syncthreads();
    int v = hist[t];
    {
        int lane = t & 63, w = t >> 6;
        int x = v;
        #pragma unroll
        for (int d = 1; d < 64; d <<= 1) {
            int y = __shfl_up(x, d, 64);
            if (lane >= d) x += y;
        }
        if (lane == 63) ws[w] = x;
        __syncthreads();
        int woff = 0;
        #pragma unroll
        for (int j = 0; j < 4; j++)
            if (j < w) woff += ws[j];
        loff[t] = woff + x - v;
    }
    int node = b * 256 + t;
    if (node < N) {
        off[node] = base + loff[t];
        dinv[node] = rsqrtf((float)v + 1.0f);  // +1 self-loop
    }
    __syncthreads();
    hist[t] = 0;  // cursors
    __syncthreads();
    for (int i = t; i < cnt; i += 256) {
        unsigned long long pr = pp[i];
        int dl = (int)(pr >> 32);
        int r = atomicAdd(&hist[dl], 1);
        csr[base + loff[dl] + r] = (int)(unsigned)pr;
    }
}

// ---------------- misc prep ----------------

__global__ __launch_bounds__(256) void graph_count_kernel(const int* __restrict__ batch,
                                                          int* __restrict__ cnt, int N) {
    __shared__ int h[256];
    int t = threadIdx.x;
    h[t] = 0;
    __syncthreads();
    int n = blockIdx.x * 256 + t;
    if (n < N) atomicAdd(&h[batch[n]], 1);
    __syncthreads();
    if (h[t] != 0) atomicAdd(&cnt[t], h[t]);
}

// x [N][128] fp32 -> Q int8 + scale0[i] = dinv[i]*rowmax/127.
__global__ __launch_bounds__(256) void prescale_q8_kernel(
        const float* __restrict__ x, const float* __restrict__ dinv,
        unsigned short* __restrict__ Q, float* __restrict__ scale, int N) {
    int node = blockIdx.x * 4 + (threadIdx.x >> 6);
    int lane = threadIdx.x & 63;
    if (node >= N) return;
    float2 v = reinterpret_cast<const float2*>(x)[(size_t)node * 64 + lane];
    float m = fmaxf(fabsf(v.x), fabsf(v.y));
    #pragma unroll
    for (int d = 32; d >= 1; d >>= 1) m = fmaxf(m, __shfl_xor(m, d, 64));
    float qinv = m > 0.f ? 127.f / m : 0.f;
    int q0 = (int)rintf(v.x * qinv), q1 = (int)rintf(v.y * qinv);
    Q[(size_t)node * 64 + lane] = (unsigned short)((q0 & 255) | ((q1 & 255) << 8));
    if (lane == 0) scale[node] = dinv[node] * m * (1.f / 127.f);
}

// W [K][256] fp32 -> WT [256][K] bf16
__global__ __launch_bounds__(256) void transpose_w_kernel(const float* __restrict__ W,
                                                          unsigned short* __restrict__ WT,
                                                          int K) {
    int idx = blockIdx.x * 256 + threadIdx.x;
    if (idx < K * 256) {
        int k = idx >> 8, n = idx & 255;
        WT[n * K + k] = f2bf(W[idx]);
    }
}

// -------- aggregation: OUT(bf16) = dinv[i] * sum(scale[s] * q8row[s]) ------
template <int VEC>  // 2 (layer1, 128-d) or 4 (layer2, 256-d)
__global__ __launch_bounds__(256) void aggregate_q8_kernel(
        const void* __restrict__ Qv, const float* __restrict__ scale,
        unsigned short* __restrict__ OUT,
        const int* __restrict__ off, const int* __restrict__ csr,
        const float* __restrict__ dinv, int N) {
    int node = __builtin_amdgcn_readfirstlane(blockIdx.x * 4 + (threadIdx.x >> 6));
    int lane = threadIdx.x & 63;
    if (node >= N) return;

    float acc[VEC];
    auto loadpay = [&](int s) -> unsigned {
        if constexpr (VEC == 4)
            return reinterpret_cast<const unsigned*>(Qv)[(size_t)s * 64 + lane];
        else
            return (unsigned)reinterpret_cast<const unsigned short*>(Qv)[(size_t)s * 64 + lane];
    };
    auto addrow = [&](unsigned v, float sc) {
        #pragma unroll
        for (int j = 0; j < VEC; j++)
            acc[j] += sc * (float)(int)(signed char)(v >> (8 * j));
    };
    {
        unsigned v = loadpay(node);
        float sc = scale[node];
        #pragma unroll
        for (int j = 0; j < VEC; j++)
            acc[j] = sc * (float)(int)(signed char)(v >> (8 * j));
    }
    int e0 = off[node], e1 = off[node + 1];
    int e = e0;
    for (; e + 16 <= e1; e += 16) {
        int s[16]; unsigned v[16]; float sc[16];
        #pragma unroll
        for (int j = 0; j < 16; j++) s[j] = csr[e + j];
        #pragma unroll
        for (int j = 0; j < 16; j++) { v[j] = loadpay(s[j]); sc[j] = scale[s[j]]; }
        #pragma unroll
        for (int j = 0; j < 16; j++) addrow(v[j], sc[j]);
    }
    if (e + 8 <= e1) {
        int s[8]; unsigned v[8]; float sc[8];
        #pragma unroll
        for (int j = 0; j < 8; j++) s[j] = csr[e + j];
        #pragma unroll
        for (int j = 0; j < 8; j++) { v[j] = loadpay(s[j]); sc[j] = scale[s[j]]; }
        #pragma unroll
        for (int j = 0; j < 8; j++) addrow(v[j], sc[j]);
        e += 8;
    }
    for (; e < e1; e++) { unsigned v = loadpay(csr[e]); addrow(v, scale[csr[e]]); }

    float di = dinv[node];
    if constexpr (VEC == 4) {
        uint2 o;
        o.x = (unsigned)f2bf(di * acc[0]) | ((unsigned)f2bf(di * acc[1]) << 16);
        o.y = (unsigned)f2bf(di * acc[2]) | ((unsigned)f2bf(di * acc[3]) << 16);
        reinterpret_cast<uint2*>(OUT)[(size_t)node * 64 + lane] = o;
    } else {
        unsigned o = (unsigned)f2bf(di * acc[0]) | ((unsigned)f2bf(di * acc[1]) << 16);
        reinterpret_cast<unsigned*>(OUT)[(size_t)node * 64 + lane] = o;
    }
}

// ---------------- MFMA GEMM (restructured) ----------------
// relu(A[M][K]@W + bias); A bf16 row-major, WT = W^T bf16 [256][K].
// 256 thr / 4 waves; tile 64 rows x 256 cols; wave w owns cols w*64..+64.
// B held in registers (loaded once per block). A double-buffered in LDS via
// pre-swizzled global_load_lds; grid-stride over row tiles, 2-phase pipeline.
// MODE 0: emit int8 Y1q + scaleOut (shfl row-max, LDS pack, dwordx4 stores).
// MODE 1: fused mean-pool into gsum (register partial sums, sorted batch).
template <int K, int MODE>
__global__ __launch_bounds__(256) void mfma_gemm_kernel(
        const unsigned short* __restrict__ A, const unsigned short* __restrict__ WT,
        const float* __restrict__ bias, const float* __restrict__ dinv,
        char* __restrict__ Cq, float* __restrict__ scaleOut,
        const int* __restrict__ batch, float* __restrict__ gsum, int M, int ntiles) {
    constexpr int KK = K / 32;            // kk steps
    constexpr int RB = K * 2;             // row bytes in LDS
    constexpr int CHUNKS = 64 * RB / 16;  // 16B chunks per tile
    constexpr int EXTRA = (MODE == 0) ? (256 * 4 + 64 * 4 + 64 * 256) : (4 * 256 * 4);
    __shared__ __align__(16) char Abuf[2][64 * RB];
    __shared__ __align__(16) char extra[EXTRA];

    const int t = threadIdx.x;
    const int lane = t & 63, w = t >> 6;
    const int lhi = lane >> 4, l15 = lane & 15;

    // --- B preload into registers (L2-hot after first blocks) ---
    bf16x8 breg[4][KK];
    #pragma unroll
    for (int nf = 0; nf < 4; nf++)
        #pragma unroll
        for (int kk = 0; kk < KK; kk++)
            breg[nf][kk] = *reinterpret_cast<const bf16x8*>(
                WT + (size_t)(w * 64 + nf * 16 + l15) * K + kk * 32 + lhi * 8);
    float bn[4];
    #pragma unroll
    for (int nf = 0; nf < 4; nf++) bn[nf] = bias[w * 64 + nf * 16 + l15];

    auto stage = [&](char* dstbuf, int tile) {
        int r0 = tile * 64;
        #pragma unroll
        for (int p = 0; p < CHUNKS / 256; p++) {
            int idx = p * 256 + t;
            int row = idx / (RB / 16);
            int cb = idx % (RB / 16);
            int sbyte = (cb * 16) ^ ((row & 7) << 4);
            const char* g = (const char*)(A + (size_t)(r0 + row) * K) + sbyte;
            __builtin_amdgcn_global_load_lds(
                (const __attribute__((address_space(1))) void*)g,
                (__attribute__((address_space(3))) void*)(dstbuf + idx * 16),
                16, 0, 0);
        }
    };

    int tile = blockIdx.x;
    if (tile >= ntiles) return;
    stage(Abuf[0], tile);
    __syncthreads();  // drains vmcnt(0)
    int c = 0;

    for (; tile < ntiles; tile += gridDim.x) {
        int nxt = tile + gridDim.x;
        if (nxt < ntiles) stage(Abuf[c ^ 1], nxt);  // overlap with compute

        f32x4 acc[4][4];
        #pragma unroll
        for (int i = 0; i < 4; i++)
            #pragma unroll
            for (int j = 0; j < 4; j++) acc[i][j] = (f32x4){0.f, 0.f, 0.f, 0.f};

        const char* buf = Abuf[c];
        #pragma unroll
        for (int kk = 0; kk < KK; kk++) {
            bf16x8 a[4];
            int kb = (kk * 32 + lhi * 8) * 2;
            #pragma unroll
            for (int mf = 0; mf < 4; mf++) {
                int row = mf * 16 + l15;
                a[mf] = *reinterpret_cast<const bf16x8*>(
                    buf + row * RB + (kb ^ ((row & 7) << 4)));
            }
            #pragma unroll
            for (int mf = 0; mf < 4; mf++)
                #pragma unroll
                for (int nf = 0; nf < 4; nf++)
                    acc[mf][nf] = __builtin_amdgcn_mfma_f32_16x16x32_bf16(
                        a[mf], breg[nf][kk], acc[mf][nf], 0, 0, 0);
        }

        int r0 = tile * 64;
        if constexpr (MODE == 0) {
            float* wmax = (float*)extra;          // [4][64]
            float* qinv = wmax + 256;             // [64]
            char* pack = (char*)(qinv + 64);      // [64][256]
            #pragma unroll
            for (int mf = 0; mf < 4; mf++)
                #pragma unroll
                for (int j = 0; j < 4; j++) {
                    float lmax = 0.f;
                    #pragma unroll
                    for (int nf = 0; nf < 4; nf++) {
                        float v = fmaxf(acc[mf][nf][j] + bn[nf], 0.f);
                        acc[mf][nf][j] = v;
                        lmax = fmaxf(lmax, v);
                    }
                    lmax = fmaxf(lmax, __shfl_xor(lmax, 1, 64));
                    lmax = fmaxf(lmax, __shfl_xor(lmax, 2, 64));
                    lmax = fmaxf(lmax, __shfl_xor(lmax, 4, 64));
                    lmax = fmaxf(lmax, __shfl_xor(lmax, 8, 64));
                    if (l15 == 0) wmax[w * 64 + mf * 16 + lhi * 4 + j] = lmax;
                }
            __syncthreads();
            if (t < 64) {
                float m4 = fmaxf(fmaxf(wmax[t], wmax[64 + t]),
                                 fmaxf(wmax[128 + t], wmax[192 + t]));
                qinv[t] = m4 > 0.f ? 127.f / m4 : 0.f;
                if (r0 + t < M) scaleOut[r0 + t] = dinv[r0 + t] * m4 * (1.f / 127.f);
            }
            __syncthreads();
            #pragma unroll
            for (int mf = 0; mf < 4; mf++)
                #pragma unroll
                for (int j = 0; j < 4; j++) {
                    int r = mf * 16 + lhi * 4 + j;
                    float qi = qinv[r];
                    #pragma unroll
                    for (int nf = 0; nf < 4; nf++)
                        pack[r * 256 + w * 64 + nf * 16 + l15] =
                            (char)(int)rintf(acc[mf][nf][j] * qi);
                }
            __syncthreads();
            #pragma unroll
            for (int p = 0; p < 4; p++) {
                int idx = p * 256 + t;
                reinterpret_cast<uint4*>(Cq + (size_t)r0 * 256)[idx] =
                    reinterpret_cast<const uint4*>(pack)[idx];
            }
        } else {
            float* psum = (float*)extra;  // [4][256]
            int gmin = batch[r0];
            int gmax = batch[min(r0 + 63, M - 1)];
            if (gmin == gmax) {
                #pragma unroll
                for (int nf = 0; nf < 4; nf++) {
                    float s = 0.f;
                    #pragma unroll
                    for (int mf = 0; mf < 4; mf++)
                        #pragma unroll
                        for (int j = 0; j < 4; j++) {
                            int m = r0 + mf * 16 + lhi * 4 + j;
                            float v = fmaxf(acc[mf][nf][j] + bn[nf], 0.f);
                            s += (m < M) ? v : 0.f;
                        }
                    psum[lhi * 256 + w * 64 + nf * 16 + l15] = s;
                }
                __syncthreads();
                float tot = psum[t] + psum[256 + t] + psum[512 + t] + psum[768 + t];
                atomicAdd(&gsum[(size_t)gmin * 256 + t], tot);
            } else {  // graph boundary tile (rare)
                #pragma unroll
                for (int mf = 0; mf < 4; mf++)
                    #pragma unroll
                    for (int j = 0; j < 4; j++) {
                        int m = r0 + mf * 16 + lhi * 4 + j;
                        if (m < M) {
                            int g = batch[m];
                            #pragma unroll
                            for (int nf = 0; nf < 4; nf++)
                                atomicAdd(&gsum[(size_t)g * 256 + w * 64 + nf * 16 + l15],
                                          fmaxf(acc[mf][nf][j] + bn[nf], 0.f));
                        }
                    }
            }
        }
        __syncthreads();  // drain next-tile stage (vmcnt 0) + protect LDS reuse
        c ^= 1;
    }
}

// ---------------- final pool-divide + classifier head ----------------

__global__ __launch_bounds__(256) void pool_final_kernel(const float* __restrict__ gsum,
                                                         const int* __restrict__ cnt,
                                                         const float* __restrict__ Wc,
                                                         const float* __restrict__ bc,
                                                         float* __restrict__ out) {
    __shared__ float gm[256];
    int g = blockIdx.x, t = threadIdx.x;
    float inv = 1.0f / fmaxf((float)cnt[g], 1.0f);
    gm[t] = gsum[g * 256 + t] * inv;
    __syncthreads();
    if (t < 200) {
        float acc = bc[t];
        #pragma unroll 8
        for (int k = 0; k < 256; k++) acc += gm[k] * Wc[k * 200 + t];
        out[g * 200 + t] = acc;
    }
}

// ---------------- driver ----------------

extern "C" void kernel_launch(void* const* d_in, const int* in_sizes, int n_in,
                              void* d_out, int out_size, void* d_ws, size_t ws_size,
                              hipStream_t stream) {
    const float* x   = (const float*)d_in[0];
    const int* ei    = (const int*)d_in[1];
    const int* batch = (const int*)d_in[2];
    const float* W1  = (const float*)d_in[4];
    const float* b1  = (const float*)d_in[5];
    const float* W2  = (const float*)d_in[6];
    const float* b2  = (const float*)d_in[7];
    const float* Wc  = (const float*)d_in[8];
    const float* bc  = (const float*)d_in[9];
    float* out = (float*)d_out;

    const int N = in_sizes[2];       // 100000
    const int E = in_sizes[1] / 2;   // 1600000
    const int G = out_size / 200;    // 64
    const int K1 = in_sizes[0] / N;  // 128
    const int Mpad = (N + 63) & ~63; // 100032
    const int NB = (N + 255) >> 8;   // 391
    const int ntiles = Mpad / 64;    // 1563
    const int* src = ei;
    const int* dst = ei + E;

    char* p = (char*)d_ws;
    auto alloc = [&](size_t bytes) -> char* {
        char* r = p;
        p += (bytes + 255) & ~(size_t)255;
        return r;
    };
    int*   off    = (int*)alloc((size_t)(N + 1) * 4);
    int*   bktCnt = (int*)alloc((size_t)NB * 4);
    int*   bktBase= (int*)alloc((size_t)NB * 4);
    int*   cnt    = (int*)alloc(256 * 4);
    float* dinv   = (float*)alloc((size_t)N * 4);
    float* scale0 = (float*)alloc((size_t)N * 4);
    float* scale1 = (float*)alloc((size_t)N * 4);
    float* gsum   = (float*)alloc((size_t)G * 256 * 4);
    int*   csr    = (int*)alloc((size_t)E * 4);
    unsigned long long* pairs = (unsigned long long*)alloc((size_t)NB * BCAP * 8);
    unsigned short* WT1 = (unsigned short*)alloc((size_t)256 * K1 * 2);
    unsigned short* WT2 = (unsigned short*)alloc((size_t)256 * 256 * 2);
    char* slotA = alloc((size_t)Mpad * 256);       // Y0q -> Y1q (int8)
    char* slotB = alloc((size_t)Mpad * 256 * 2);   // a1 -> a2 (bf16)
    unsigned short* Y0q = (unsigned short*)slotA;
    char*           Y1q = slotA;
    unsigned short* a1  = (unsigned short*)slotB;
    unsigned short* a2  = (unsigned short*)slotB;

    hipMemsetAsync(bktCnt, 0, (size_t)NB * 4, stream);
    hipMemsetAsync(cnt, 0, 256 * 4, stream);
    hipMemsetAsync(gsum, 0, (size_t)G * 256 * 4, stream);

    int blkN = (N + 255) / 256;
    bucket_scatter_kernel<<<(E + P1_CHUNK - 1) / P1_CHUNK, 256, 0, stream>>>(
        src, dst, bktCnt, pairs, E, NB);
    bucket_scan_kernel<<<1, 512, 0, stream>>>(bktCnt, bktBase, off, NB, N, E);
    fine_place_kernel<<<NB, 256, 0, stream>>>(pairs, bktCnt, bktBase, off, dinv, csr, N);

    graph_count_kernel<<<blkN, 256, 0, stream>>>(batch, cnt, N);
    transpose_w_kernel<<<(K1 * 256 + 255) / 256, 256, 0, stream>>>(W1, WT1, K1);
    transpose_w_kernel<<<(256 * 256 + 255) / 256, 256, 0, stream>>>(W2, WT2, 256);
    prescale_q8_kernel<<<(N + 3) / 4, 256, 0, stream>>>(x, dinv, Y0q, scale0, N);

    // layer 1 (K=128, MODE0 int8 out): 3 blocks/CU
    aggregate_q8_kernel<2><<<(N + 3) / 4, 256, 0, stream>>>(Y0q, scale0, a1, off, csr, dinv, N);
    mfma_gemm_kernel<128, 0><<<768, 256, 0, stream>>>(
        a1, WT1, b1, dinv, Y1q, scale1, nullptr, nullptr, N, ntiles);
    // layer 2 (K=256, MODE1 fused pool): 2 blocks/CU
    aggregate_q8_kernel<4><<<(N + 3) / 4, 256, 0, stream>>>(Y1q, scale1, a2, off, csr, dinv, N);
    mfma_gemm_kernel<256, 1><<<512, 256, 0, stream>>>(
        a2, WT2, b2, nullptr, nullptr, nullptr, batch, gsum, N, ntiles);
    // head
    pool_final_kernel<<<G, 256, 0, stream>>>(gsum, cnt, Wc, bc, out);
}